// Round 1
// baseline (472.098 us; speedup 1.0000x reference)
//
#include <hip/hip_runtime.h>

// 2-D DCT-II, B=128 batches of 512x512 fp32.
// Y_b = scale .* (C @ X_b @ C^T), C[k][i] = cos(pi*(2i+1)*k/1024).
// Implemented as two GEMM passes with split-precision bf16 MFMA:
//   A*B ~= Ahi*Bhi + Ahi*Blo + Alo*Bhi   (hi/lo bf16 split, ~1e-5 rel err)
// Pass 1: W[b,q,m] = sum_n X[b,m,n] C[q,n]   (transposed store, split bf16 out)
// Pass 2: Y[b,p,q] = scale * sum_m W[b,q,m] C[p,m]  (transposed store, fp32 out)
// Both passes: 128x128 tile, BK=32, 4 waves (64x64 out each), double-buffered
// LDS, XOR-swizzled tiles (2-way-free ds_read_b128), global_load_lds width 16
// with pre-swizzled global source for the bf16 operands.

typedef unsigned short u16;
typedef __attribute__((ext_vector_type(8))) short short8;
typedef __attribute__((ext_vector_type(4))) float float4v;
typedef __attribute__((ext_vector_type(4))) unsigned short ushort4v;

typedef const __attribute__((address_space(1))) void* gptr_t;
typedef __attribute__((address_space(3))) void* lptr_t;

__device__ __forceinline__ u16 f2bf(float f) {
  unsigned x = __float_as_uint(f);
  unsigned r = x + 0x7FFFu + ((x >> 16) & 1u);  // round-to-nearest-even
  return (u16)(r >> 16);
}
__device__ __forceinline__ float bf2f(u16 h) {
  return __uint_as_float(((unsigned)h) << 16);
}

__device__ __forceinline__ void gload16(const void* g, void* l) {
  __builtin_amdgcn_global_load_lds((gptr_t)g, (lptr_t)l, 16, 0, 0);
}

// C[k][i], replicating the reference's fp32 arithmetic exactly:
// arg = ((pi_f32 * (2i+1)) * k) / 1024, all fp32-rounded; then cos.
__global__ void dct_coeff_kernel(u16* __restrict__ chi, u16* __restrict__ clo) {
  int idx = blockIdx.x * blockDim.x + threadIdx.x;  // exactly 512*512 threads
  int k = idx >> 9, i = idx & 511;
  float a = 3.14159274101257324f * (float)(2 * i + 1);
  float arg = (a * (float)k) * (1.0f / 1024.0f);  // /1024 is exact (pow2)
  float c = cosf(arg);
  u16 h = f2bf(c);
  chi[idx] = h;
  clo[idx] = f2bf(c - bf2f(h));
}

template <int PASS>
__global__ __launch_bounds__(256, 2) void dct_gemm_kernel(
    const float* __restrict__ X,                                  // pass 1 A
    const u16* __restrict__ AHI, const u16* __restrict__ ALO,     // pass 2 A
    const u16* __restrict__ CHI, const u16* __restrict__ CLO,     // B (coeffs)
    u16* __restrict__ WHI, u16* __restrict__ WLO,                 // pass 1 out
    float* __restrict__ Y) {                                      // pass 2 out
  // [buf][Ahi,Alo,Bhi,Blo][128 rows x 32 k] bf16 = 64 KiB total
  __shared__ u16 lds[2][4][128 * 32];

  const int tid = threadIdx.x;
  const int w = tid >> 6;   // wave 0..3
  const int ln = tid & 63;  // lane
  const int ln15 = ln & 15;
  const int s0 = ln >> 4;  // 16B k-slot for MFMA fragments
  const int tile_n = blockIdx.x & 3;
  const int tile_m = blockIdx.x >> 2;
  const int row0 = tile_m * 128;  // global A-row base (65536 rows total)
  const int n0 = tile_n * 128;    // C-row base (output col base)
  const int wm = w >> 1, wn = w & 1;

  float4v acc[4][4];
#pragma unroll
  for (int i = 0; i < 4; ++i)
#pragma unroll
    for (int j = 0; j < 4; ++j) {
      float4v z = {0.f, 0.f, 0.f, 0.f};
      acc[i][j] = z;
    }

  // Stage a 128x32 bf16 tile from a row-major [*,512] bf16 matrix via
  // global_load_lds. LDS layout: elem = row*32 + slot*8 (+0..7), where the
  // stored slot s holds global slot s ^ f(row), f(row)=(row>>1)&3 (so the
  // swizzled ds_read below is 2-way/free). Achieved by pre-swizzling the
  // per-lane GLOBAL address; LDS dest stays linear (wave base + lane*16B).
  auto stage_bf = [&](const u16* src, int gr0, int k0, u16* ldst) {
#pragma unroll
    for (int j2 = 0; j2 < 2; ++j2) {
      const int trow = w * 32 + j2 * 16 + (ln >> 2);              // tile row
      const int sg = (ln & 3) ^ ((trow >> 1) & 3);                // global slot
      const u16* g = src + (size_t)(gr0 + trow) * 512 + k0 + sg * 8;
      u16* l = ldst + (w * 32 + j2 * 16) * 32;  // wave-uniform chunk base
      gload16(g, l);
    }
  };

  // Pass-1 A: fp32 source, hi/lo bf16 split in registers, swizzled ds_write.
  auto stage_a1 = [&](int k0, u16* lh, u16* ll) {
#pragma unroll
    for (int j = 0; j < 4; ++j) {
      const int trow = w * 32 + j * 8 + (ln >> 3);
      const int s16 = ln & 7;  // 16B fp32 chunk (4 floats) within the row
      const float4v v =
          *(const float4v*)(X + (size_t)(row0 + trow) * 512 + k0 + s16 * 4);
      ushort4v hh, lv;
#pragma unroll
      for (int e = 0; e < 4; ++e) {
        float f = v[e];
        u16 h = f2bf(f);
        hh[e] = h;
        lv[e] = f2bf(f - bf2f(h));
      }
      // fp32 chunk s16 -> bf16 slot s16>>1 (half s16&1), slot XOR-swizzled
      const int off =
          trow * 32 + (((s16 >> 1) ^ ((trow >> 1) & 3)) << 3) + (s16 & 1) * 4;
      *(ushort4v*)(lh + off) = hh;
      *(ushort4v*)(ll + off) = lv;
    }
  };

  auto stage_all = [&](int buf, int t) {
    const int k0 = t * 32;
    if constexpr (PASS == 1) {
      stage_a1(k0, lds[buf][0], lds[buf][1]);
    } else {
      stage_bf(AHI, row0, k0, lds[buf][0]);
      stage_bf(ALO, row0, k0, lds[buf][1]);
    }
    stage_bf(CHI, n0, k0, lds[buf][2]);
    stage_bf(CLO, n0, k0, lds[buf][3]);
  };

  auto compute = [&](int buf) {
    const u16* lAh = lds[buf][0];
    const u16* lAl = lds[buf][1];
    const u16* lBh = lds[buf][2];
    const u16* lBl = lds[buf][3];
    short8 ah[4], al[4], bh[4], bl[4];
#pragma unroll
    for (int i = 0; i < 4; ++i) {
      const int ra = wm * 64 + i * 16 + ln15;
      const int oa = ra * 32 + ((s0 ^ ((ra >> 1) & 3)) << 3);
      ah[i] = *(const short8*)(lAh + oa);
      al[i] = *(const short8*)(lAl + oa);
      const int rb = wn * 64 + i * 16 + ln15;
      const int ob = rb * 32 + ((s0 ^ ((rb >> 1) & 3)) << 3);
      bh[i] = *(const short8*)(lBh + ob);
      bl[i] = *(const short8*)(lBl + ob);
    }
#pragma unroll
    for (int i = 0; i < 4; ++i)
#pragma unroll
      for (int j = 0; j < 4; ++j) {
        acc[i][j] =
            __builtin_amdgcn_mfma_f32_16x16x32_bf16(ah[i], bh[j], acc[i][j], 0, 0, 0);
        acc[i][j] =
            __builtin_amdgcn_mfma_f32_16x16x32_bf16(ah[i], bl[j], acc[i][j], 0, 0, 0);
        acc[i][j] =
            __builtin_amdgcn_mfma_f32_16x16x32_bf16(al[i], bh[j], acc[i][j], 0, 0, 0);
      }
  };

  // 2-phase double-buffered K loop (16 steps of BK=32)
  stage_all(0, 0);
  __syncthreads();
  for (int t = 0; t < 16; ++t) {
    const int cur = t & 1;
    if (t < 15) stage_all(cur ^ 1, t + 1);
    compute(cur);
    __syncthreads();
  }

  // Epilogue: transposed store. G[i][j] -> Out[b, j, i&511].
  // D frag layout (m89): col = lane&15, row = (lane>>4)*4 + reg.
  const float RS2 = 0.70710678118654752440f;
#pragma unroll
  for (int i = 0; i < 4; ++i) {
    const int il = wm * 64 + i * 16 + (ln >> 4) * 4;
    const int gi = row0 + il;
    const int b = gi >> 9;
    const int qm = gi & 511;  // m (pass 1) / q (pass 2)
#pragma unroll
    for (int j = 0; j < 4; ++j) {
      const int jglob = n0 + wn * 64 + j * 16 + ln15;  // q (pass 1) / p (pass 2)
      const size_t idx = (size_t)b * 262144 + (size_t)jglob * 512 + qm;
      const float4v v = acc[i][j];
      if constexpr (PASS == 1) {
        ushort4v h, lo;
#pragma unroll
        for (int e = 0; e < 4; ++e) {
          float f = v[e];
          u16 hh = f2bf(f);
          h[e] = hh;
          lo[e] = f2bf(f - bf2f(hh));
        }
        *(ushort4v*)(WHI + idx) = h;
        *(ushort4v*)(WLO + idx) = lo;
      } else {
        const float sj = (jglob == 0) ? RS2 : 1.0f;
        const float sc = 0.00390625f * sj;  // 2/M = 1/256
        float4v o;
#pragma unroll
        for (int e = 0; e < 4; ++e) {
          o[e] = v[e] * sc * ((qm + e) == 0 ? RS2 : 1.0f);
        }
        *(float4v*)(Y + idx) = o;
      }
    }
  }
}

extern "C" void kernel_launch(void* const* d_in, const int* in_sizes, int n_in,
                              void* d_out, int out_size, void* d_ws, size_t ws_size,
                              hipStream_t stream) {
  const float* img = (const float*)d_in[0];
  float* out = (float*)d_out;
  char* ws = (char*)d_ws;

  // Workspace layout (needs 135,266,304 bytes):
  //   [0,       512K)  Chi   (512*512 bf16)
  //   [512K,    1M)    Clo
  //   [1M,      1M+64M...)  Whi (128*512*512 bf16)
  //   [+67108864)      Wlo
  u16* Chi = (u16*)(ws);
  u16* Clo = (u16*)(ws + 524288);
  u16* Whi = (u16*)(ws + (1u << 20));
  u16* Wlo = (u16*)(ws + (1u << 20) + 67108864u);

  dct_coeff_kernel<<<1024, 256, 0, stream>>>(Chi, Clo);
  dct_gemm_kernel<1><<<2048, 256, 0, stream>>>(img, nullptr, nullptr, Chi, Clo,
                                               Whi, Wlo, nullptr);
  dct_gemm_kernel<2><<<2048, 256, 0, stream>>>(nullptr, Whi, Wlo, Chi, Clo,
                                               nullptr, nullptr, out);
}

// Round 2
// 302.330 us; speedup vs baseline: 1.5615x; 1.5615x over previous
//
#include <hip/hip_runtime.h>

// 2-D DCT-II, B=128 batches of 512x512 fp32.
// Y_b = scale .* (C @ X_b @ C^T), C[k][i] = cos(pi*(2i+1)*k/1024).
// Two plain f16 MFMA GEMM passes (f16 rounding error ~2e-4 rms per pass,
// absmax contribution ~2e-3 -- far below the measured 0.031 comparison floor).
// Pass 1: W[b,q,m] = sum_n X[b,m,n] C[q,n]   (transposed store, f16 out)
// Pass 2: Y[b,p,q] = scale * sum_m W[b,q,m] C[p,m]  (transposed store, fp32)
// 128x128 tile, BK=32, 4 waves (64x64 out each), double-buffered 32KB LDS
// (3 blocks/CU), XOR-swizzled tiles, global_load_lds w=16 with pre-swizzled
// global source for f16 operands, XCD-bijective block swizzle so the 4
// tile_n blocks sharing an A row-panel land on the same XCD (L2 reuse).

typedef unsigned short u16;
typedef __attribute__((ext_vector_type(8))) short short8;
typedef __attribute__((ext_vector_type(4))) float float4v;
typedef __attribute__((ext_vector_type(4))) unsigned short ushort4v;

typedef const __attribute__((address_space(1))) void* gptr_t;
typedef __attribute__((address_space(3))) void* lptr_t;

__device__ __forceinline__ u16 f2h(float f) {
  _Float16 h = (_Float16)f;  // v_cvt_f16_f32, RTE
  return __builtin_bit_cast(u16, h);
}

__device__ __forceinline__ void gload16(const void* g, void* l) {
  __builtin_amdgcn_global_load_lds((gptr_t)g, (lptr_t)l, 16, 0, 0);
}

// C[k][i] in f16, replicating the reference's fp32 argument arithmetic:
// arg = ((pi_f32 * (2i+1)) * k) / 1024, all fp32-rounded; then cos.
__global__ void dct_coeff_kernel(u16* __restrict__ ch) {
  int idx = blockIdx.x * blockDim.x + threadIdx.x;  // exactly 512*512 threads
  int k = idx >> 9, i = idx & 511;
  float a = 3.14159274101257324f * (float)(2 * i + 1);
  float arg = (a * (float)k) * (1.0f / 1024.0f);  // /1024 exact (pow2)
  ch[idx] = f2h(cosf(arg));
}

template <int PASS>
__global__ __launch_bounds__(256, 3) void dct_gemm_kernel(
    const float* __restrict__ X,   // pass 1 A (fp32 img)
    const u16* __restrict__ W,     // pass 2 A (f16 intermediate)
    const u16* __restrict__ C,     // B (f16 coeffs)
    u16* __restrict__ Wout,        // pass 1 out
    float* __restrict__ Y) {       // pass 2 out
  // [buf][A,B][128 rows x 32 k] f16 = 32 KiB total
  __shared__ u16 lds[2][2][128 * 32];

  const int tid = threadIdx.x;
  const int w = tid >> 6;   // wave 0..3
  const int ln = tid & 63;  // lane
  const int ln15 = ln & 15;
  const int s0 = ln >> 4;  // 16B k-slot for MFMA fragments
  // XCD-bijective swizzle: blocks congruent mod 8 share an XCD (round-robin
  // dispatch); give each XCD a contiguous range of virt so the 4 tile_n
  // siblings of each tile_m are co-resident -> A-panel L2 hits.
  const int virt = (blockIdx.x & 7) * 256 + (blockIdx.x >> 3);
  const int tile_n = virt & 3;
  const int tile_m = virt >> 2;
  const int row0 = tile_m * 128;  // global A-row base (65536 rows total)
  const int n0 = tile_n * 128;    // C-row base (output col base)
  const int wm = w >> 1, wn = w & 1;

  float4v acc[4][4];
#pragma unroll
  for (int i = 0; i < 4; ++i)
#pragma unroll
    for (int j = 0; j < 4; ++j) {
      float4v z = {0.f, 0.f, 0.f, 0.f};
      acc[i][j] = z;
    }

  // Stage a 128x32 f16 tile from a row-major [*,512] f16 matrix via
  // global_load_lds. LDS layout: elem = row*32 + slot*8 (+0..7); stored
  // slot s holds global slot s ^ f(row), f(row)=(row>>1)&3. Achieved by
  // pre-swizzling the per-lane GLOBAL address; LDS dest stays linear.
  auto stage_bf = [&](const u16* src, int gr0, int k0, u16* ldst) {
#pragma unroll
    for (int j2 = 0; j2 < 2; ++j2) {
      const int trow = w * 32 + j2 * 16 + (ln >> 2);    // tile row
      const int sg = (ln & 3) ^ ((trow >> 1) & 3);      // global slot
      const u16* g = src + (size_t)(gr0 + trow) * 512 + k0 + sg * 8;
      u16* l = ldst + (w * 32 + j2 * 16) * 32;  // wave-uniform chunk base
      gload16(g, l);
    }
  };

  // Pass-1 A: fp32 source, f16 convert in registers, swizzled ds_write.
  auto stage_a1 = [&](int k0, u16* lh) {
#pragma unroll
    for (int j = 0; j < 4; ++j) {
      const int trow = w * 32 + j * 8 + (ln >> 3);
      const int s16 = ln & 7;  // 16B fp32 chunk (4 floats) within the row
      const float4v v =
          *(const float4v*)(X + (size_t)(row0 + trow) * 512 + k0 + s16 * 4);
      ushort4v hh;
#pragma unroll
      for (int e = 0; e < 4; ++e) hh[e] = f2h(v[e]);
      // fp32 chunk s16 -> f16 slot s16>>1 (half s16&1), slot XOR-swizzled
      const int off =
          trow * 32 + (((s16 >> 1) ^ ((trow >> 1) & 3)) << 3) + (s16 & 1) * 4;
      *(ushort4v*)(lh + off) = hh;
    }
  };

  auto stage_all = [&](int buf, int t) {
    const int k0 = t * 32;
    if constexpr (PASS == 1) {
      stage_a1(k0, lds[buf][0]);
    } else {
      stage_bf(W, row0, k0, lds[buf][0]);
    }
    stage_bf(C, n0, k0, lds[buf][1]);
  };

  auto compute = [&](int buf) {
    const u16* lA = lds[buf][0];
    const u16* lB = lds[buf][1];
    short8 a[4], b[4];
#pragma unroll
    for (int i = 0; i < 4; ++i) {
      const int ra = wm * 64 + i * 16 + ln15;
      const int oa = ra * 32 + ((s0 ^ ((ra >> 1) & 3)) << 3);
      a[i] = *(const short8*)(lA + oa);
      const int rb = wn * 64 + i * 16 + ln15;
      const int ob = rb * 32 + ((s0 ^ ((rb >> 1) & 3)) << 3);
      b[i] = *(const short8*)(lB + ob);
    }
#pragma unroll
    for (int i = 0; i < 4; ++i)
#pragma unroll
      for (int j = 0; j < 4; ++j)
        acc[i][j] =
            __builtin_amdgcn_mfma_f32_16x16x32_f16(a[i], b[j], acc[i][j], 0, 0, 0);
  };

  // 2-phase double-buffered K loop (16 steps of BK=32)
  stage_all(0, 0);
  __syncthreads();
  for (int t = 0; t < 16; ++t) {
    const int cur = t & 1;
    if (t < 15) stage_all(cur ^ 1, t + 1);
    compute(cur);
    __syncthreads();
  }

  // Epilogue: transposed store. G[i][j] -> Out[b, j, i&511].
  // D frag layout (m89): col = lane&15, row = (lane>>4)*4 + reg.
  const float RS2 = 0.70710678118654752440f;
#pragma unroll
  for (int i = 0; i < 4; ++i) {
    const int il = wm * 64 + i * 16 + (ln >> 4) * 4;
    const int gi = row0 + il;
    const int b = gi >> 9;
    const int qm = gi & 511;  // m (pass 1) / q (pass 2)
#pragma unroll
    for (int j = 0; j < 4; ++j) {
      const int jglob = n0 + wn * 64 + j * 16 + ln15;  // q (pass 1) / p (pass 2)
      const size_t idx = (size_t)b * 262144 + (size_t)jglob * 512 + qm;
      const float4v v = acc[i][j];
      if constexpr (PASS == 1) {
        ushort4v h;
#pragma unroll
        for (int e = 0; e < 4; ++e) h[e] = f2h(v[e]);
        *(ushort4v*)(Wout + idx) = h;
      } else {
        const float sj = (jglob == 0) ? RS2 : 1.0f;
        const float sc = 0.00390625f * sj;  // 2/M = 1/256
        float4v o;
#pragma unroll
        for (int e = 0; e < 4; ++e)
          o[e] = v[e] * sc * ((qm + e) == 0 ? RS2 : 1.0f);
        *(float4v*)(Y + idx) = o;
      }
    }
  }
}

extern "C" void kernel_launch(void* const* d_in, const int* in_sizes, int n_in,
                              void* d_out, int out_size, void* d_ws, size_t ws_size,
                              hipStream_t stream) {
  const float* img = (const float*)d_in[0];
  float* out = (float*)d_out;
  char* ws = (char*)d_ws;

  // Workspace layout (needs 68,157,440 bytes):
  //   [0,    512K)        Cf16 (512*512 f16)
  //   [1M,   1M+64M)      W    (128*512*512 f16)
  u16* Cf = (u16*)(ws);
  u16* W = (u16*)(ws + (1u << 20));

  dct_coeff_kernel<<<1024, 256, 0, stream>>>(Cf);
  dct_gemm_kernel<1><<<2048, 256, 0, stream>>>(img, nullptr, Cf, W, nullptr);
  dct_gemm_kernel<2><<<2048, 256, 0, stream>>>(nullptr, W, Cf, nullptr, out);
}

// Round 4
// 289.851 us; speedup vs baseline: 1.6288x; 1.0431x over previous
//
#include <hip/hip_runtime.h>

// 2-D DCT-II, B=128 batches of 512x512 fp32.
// Y_b = scale .* (C @ X_b @ C^T), C[k][i] = cos(pi*(2i+1)*k/1024).
// Two f16 MFMA GEMM passes with a 3-deep counted-vmcnt pipeline (T3+T4):
//   Pass 1: W[b,q,m] = sum_n X[b,m,n] C[q,n]  (A = fp32 X staged raw via
//           global_load_lds, converted f32->f16 after ds_read; transposed
//           f16 store)
//   Pass 2: Y[b,p,q] = scale * sum_m W[b,q,m] C[p,m]  (pure f16, fp32 store)
// 256x256 tile, BK=32, 512 thr / 8 waves (wave-tile 128x64, acc 8x4 frags).
// 3 LDS K-tile buffers, stage distance 2; per tile: ONE raw s_barrier and
// ONE s_waitcnt vmcnt(6|4) (= loads of tile T+1 still in flight; never 0 in
// steady state). XOR-swizzled LDS via pre-swizzled global source (rule #21).
// XCD-bijective block swizzle pairs the two tile_n blocks of each tile_m on
// one XCD (A-panel fetched once -> L2 hit for the sibling).

typedef unsigned short u16;
typedef __attribute__((ext_vector_type(8))) short short8;
typedef __attribute__((ext_vector_type(4))) float float4v;
typedef __attribute__((ext_vector_type(4))) unsigned short ushort4v;

typedef const __attribute__((address_space(1))) void* gptr_t;
typedef __attribute__((address_space(3))) void* lptr_t;

__device__ __forceinline__ u16 f2h(float f) {
  _Float16 h = (_Float16)f;  // v_cvt_f16_f32, RTE
  return __builtin_bit_cast(u16, h);
}

__device__ __forceinline__ void gload16(const void* g, void* l) {
  __builtin_amdgcn_global_load_lds((gptr_t)g, (lptr_t)l, 16, 0, 0);
}

// C[k][i] in f16, replicating the reference's fp32 argument arithmetic.
__global__ void dct_coeff_kernel(u16* __restrict__ ch) {
  int idx = blockIdx.x * blockDim.x + threadIdx.x;  // 512*512 threads
  int k = idx >> 9, i = idx & 511;
  float a = 3.14159274101257324f * (float)(2 * i + 1);
  float arg = (a * (float)k) * (1.0f / 1024.0f);
  ch[idx] = f2h(cosf(arg));
}

template <int PASS>
__global__ __launch_bounds__(512, 2) void dct_gemm_kernel(
    const float* __restrict__ X,   // pass 1 A (fp32 img)
    const u16* __restrict__ W,     // pass 2 A (f16 intermediate)
    const u16* __restrict__ C,     // B (f16 coeffs)
    u16* __restrict__ Wout,        // pass 1 out
    float* __restrict__ Y) {       // pass 2 out
  constexpr int ABYTES = (PASS == 1) ? (256 * 32 * 4) : (256 * 32 * 2);
  constexpr int BBYTES = 256 * 32 * 2;
  // 3 K-tile ring buffers: pass1 3*(32K+16K)=144KB, pass2 3*32K=96KB.
  __shared__ __align__(1024) char lds_raw[3 * (ABYTES + BBYTES)];

  const int tid = threadIdx.x;
  const int w = tid >> 6;    // wave 0..7
  const int ln = tid & 63;   // lane
  const int ln15 = ln & 15;
  const int s0 = ln >> 4;    // k-slot 0..3 (8 f16 each)
  // XCD-bijective swizzle (512 blocks, 512%8==0): XCD x gets virt
  // [x*64, x*64+64). tile_n siblings (virt 2k,2k+1) share an XCD.
  const int virt = (blockIdx.x & 7) * 64 + (blockIdx.x >> 3);
  const int tile_n = virt & 1;
  const int tile_m = virt >> 1;   // 0..255
  const int row0 = tile_m * 256;  // global A-row base (65536 rows)
  const int n0 = tile_n * 256;    // C-row base (output col base)
  const int wm = w >> 2, wn = w & 3;  // 2 x 4 wave grid

  auto bufA32 = [&](int i) { return (float*)(lds_raw + i * (ABYTES + BBYTES)); };
  auto bufA16 = [&](int i) { return (u16*)(lds_raw + i * (ABYTES + BBYTES)); };
  auto bufB   = [&](int i) { return (u16*)(lds_raw + i * (ABYTES + BBYTES) + ABYTES); };

  float4v acc[8][4];
#pragma unroll
  for (int i = 0; i < 8; ++i)
#pragma unroll
    for (int j = 0; j < 4; ++j) {
      float4v z = {0.f, 0.f, 0.f, 0.f};
      acc[i][j] = z;
    }

  // --- staging (all per-wave 1KB issues; LDS dest linear, global pre-swizzled)
  // f16 tile 256x32 (64B/row, 4 chunks): seg covers rows seg*16..+15.
  // stored chunk c' holds global chunk c'^((row>>1)&3)  [round-2-proven].
  auto stage_f16 = [&](const u16* src, int gr0, int k0, u16* dst, int seg) {
    const int row = seg * 16 + (ln >> 2);
    const int cg = (ln & 3) ^ ((row >> 1) & 3);
    gload16(src + (size_t)(gr0 + row) * 512 + k0 + cg * 8, dst + seg * 512);
  };
  // fp32 tile 256x32 (128B/row, 8 chunks): seg covers rows seg*8..+7.
  // stored chunk c' holds global chunk c'^(row&7).
  auto stage_f32 = [&](int k0, float* dst, int seg) {
    const int row = seg * 8 + (ln >> 3);
    const int cg = (ln & 7) ^ (row & 7);
    gload16(X + (size_t)(row0 + row) * 512 + k0 + cg * 4, dst + seg * 256);
  };

  // Per-phase staging of tile t (vmcnt: pass1 3 loads/phase, pass2 2).
  auto stage_phase = [&](int t, int ph) {
    const int k0 = t * 32;
    const int bi = t % 3;
    if constexpr (PASS == 1) {
      float* dA = bufA32(bi);
      u16* dB = bufB(bi);
      if (ph == 0) {
        stage_f32(k0, dA, w * 4 + 0);
        stage_f32(k0, dA, w * 4 + 1);
        stage_f16(C, n0, k0, dB, w * 2 + 0);
      } else {
        stage_f32(k0, dA, w * 4 + 2);
        stage_f32(k0, dA, w * 4 + 3);
        stage_f16(C, n0, k0, dB, w * 2 + 1);
      }
    } else {
      u16* dA = bufA16(bi);
      u16* dB = bufB(bi);
      if (ph == 0) {
        stage_f16(W, row0, k0, dA, w * 2 + 0);
        stage_f16(C, n0, k0, dB, w * 2 + 0);
      } else {
        stage_f16(W, row0, k0, dA, w * 2 + 1);
        stage_f16(C, n0, k0, dB, w * 2 + 1);
      }
    }
  };

  auto load_B = [&](int t, short8* b) {
    const u16* lB = bufB(t % 3);
#pragma unroll
    for (int j = 0; j < 4; ++j) {
      const int rb = wn * 64 + j * 16 + ln15;
      const int ob = rb * 32 + ((s0 ^ ((rb >> 1) & 3)) << 3);
      b[j] = *(const short8*)(lB + ob);
    }
  };

  auto load_A_phase = [&](int t, int mh, short8* a) {
    if constexpr (PASS == 1) {
      const float* lA = bufA32(t % 3);
#pragma unroll
      for (int i = 0; i < 4; ++i) {
        const int r = wm * 128 + mh * 64 + i * 16 + ln15;
        const int m = r & 7;
        const float4v f0 = *(const float4v*)(lA + r * 32 + (((2 * s0) ^ m) << 2));
        const float4v f1 = *(const float4v*)(lA + r * 32 + ((((2 * s0) | 1) ^ m) << 2));
        short8 v;
#pragma unroll
        for (int e = 0; e < 4; ++e) {
          v[e] = (short)f2h(f0[e]);
          v[4 + e] = (short)f2h(f1[e]);
        }
        a[i] = v;
      }
    } else {
      const u16* lA = bufA16(t % 3);
#pragma unroll
      for (int i = 0; i < 4; ++i) {
        const int r = wm * 128 + mh * 64 + i * 16 + ln15;
        const int o = r * 32 + ((s0 ^ ((r >> 1) & 3)) << 3);
        a[i] = *(const short8*)(lA + o);
      }
    }
  };

  // Prologue: stage tiles 0 and 1 (distance-2 ring fill).
  stage_phase(0, 0);
  stage_phase(0, 1);
  stage_phase(1, 0);
  stage_phase(1, 1);

#pragma unroll
  for (int T = 0; T < 16; ++T) {
    // Drain own tile-T loads; leave tile T+1's (6 or 4) in flight.
    if (T < 15) {
      if constexpr (PASS == 1)
        asm volatile("s_waitcnt vmcnt(6)" ::: "memory");
      else
        asm volatile("s_waitcnt vmcnt(4)" ::: "memory");
    } else {
      asm volatile("s_waitcnt vmcnt(0)" ::: "memory");
    }
    asm volatile("s_barrier" ::: "memory");  // all waves' tile-T writes visible

    short8 a[4], b[4];
    load_B(T, b);
    load_A_phase(T, 0, a);
    if (T < 14) stage_phase(T + 2, 0);
    __builtin_amdgcn_s_setprio(1);
#pragma unroll
    for (int i = 0; i < 4; ++i)
#pragma unroll
      for (int j = 0; j < 4; ++j)
        acc[i][j] =
            __builtin_amdgcn_mfma_f32_16x16x32_f16(a[i], b[j], acc[i][j], 0, 0, 0);
    __builtin_amdgcn_s_setprio(0);

    load_A_phase(T, 1, a);
    if (T < 14) stage_phase(T + 2, 1);
    __builtin_amdgcn_s_setprio(1);
#pragma unroll
    for (int i = 0; i < 4; ++i)
#pragma unroll
      for (int j = 0; j < 4; ++j)
        acc[4 + i][j] = __builtin_amdgcn_mfma_f32_16x16x32_f16(a[i], b[j],
                                                               acc[4 + i][j], 0, 0, 0);
    __builtin_amdgcn_s_setprio(0);
  }

  // Epilogue: transposed store. frag D layout: col=lane&15, row=(lane>>4)*4+reg.
  const float RS2 = 0.70710678118654752440f;
#pragma unroll
  for (int i = 0; i < 8; ++i) {
    const int gi = row0 + wm * 128 + i * 16 + (ln >> 4) * 4;
    const int b = gi >> 9;
    const int qm = gi & 511;  // m (pass 1) / q (pass 2)
#pragma unroll
    for (int j = 0; j < 4; ++j) {
      const int jglob = n0 + wn * 64 + j * 16 + ln15;  // q (p1) / p (p2)
      const size_t idx = (size_t)b * 262144 + (size_t)jglob * 512 + qm;
      const float4v v = acc[i][j];
      if constexpr (PASS == 1) {
        ushort4v h;
#pragma unroll
        for (int e = 0; e < 4; ++e) h[e] = f2h(v[e]);
        *(ushort4v*)(Wout + idx) = h;
      } else {
        const float sj = (jglob == 0) ? RS2 : 1.0f;
        const float sc = 0.00390625f * sj;  // 2/M = 1/256
        float4v o;
#pragma unroll
        for (int e = 0; e < 4; ++e)
          o[e] = v[e] * sc * ((qm + e) == 0 ? RS2 : 1.0f);
        *(float4v*)(Y + idx) = o;
      }
    }
  }
}

extern "C" void kernel_launch(void* const* d_in, const int* in_sizes, int n_in,
                              void* d_out, int out_size, void* d_ws, size_t ws_size,
                              hipStream_t stream) {
  const float* img = (const float*)d_in[0];
  float* out = (float*)d_out;
  char* ws = (char*)d_ws;

  // Workspace: [0,512K) C f16; [1M, 1M+64M) W f16.
  u16* Cf = (u16*)(ws);
  u16* Wb = (u16*)(ws + (1u << 20));

  dct_coeff_kernel<<<1024, 256, 0, stream>>>(Cf);
  dct_gemm_kernel<1><<<512, 512, 0, stream>>>(img, nullptr, Cf, Wb, nullptr);
  dct_gemm_kernel<2><<<512, 512, 0, stream>>>(nullptr, Wb, Cf, nullptr, out);
}